// Round 8
// baseline (1853.690 us; speedup 1.0000x reference)
//
#include <hip/hip_runtime.h>

#define NG 128     // num graphs
#define NL 4       // layers
#define ND 3       // dims
#define BSHIFT 8   // 256 nodes per bucket
#define MAXNB 512  // supports N <= 131072

// ---------------- zero binCount + pooled (capture-safe) ----------------
__global__ __launch_bounds__(256) void zero_kernel(
    int* __restrict__ binCount, float* __restrict__ pooled, int NB, int P) {
    int i = blockIdx.x * 256 + threadIdx.x;
    if (i < NB) binCount[i] = 0;
    if (i < P) pooled[i] = 0.f;
}

// ---------------- bucket histogram (LDS-preaggregated) ----------------
__global__ __launch_bounds__(256) void binhist_kernel(
    const int* __restrict__ eidx, int* __restrict__ binCount, int E, int NB) {
    __shared__ int cnt[MAXNB];
    int t = threadIdx.x;
    for (int i = t; i < MAXNB; i += 256) cnt[i] = 0;
    __syncthreads();
    int base = blockIdx.x * 4096;
    int end = base + 4096; if (end > E) end = E;
    for (int i = base + t; i < end; i += 256)
        atomicAdd(&cnt[eidx[E + i] >> BSHIFT], 1);
    __syncthreads();
    for (int i = t; i < NB; i += 256)
        if (cnt[i]) atomicAdd(&binCount[i], cnt[i]);
}

// ---------------- exclusive scan of bucket counts (single block, 512 thr) ----------------
__global__ __launch_bounds__(512) void binscan_kernel(
    const int* __restrict__ binCount, int* __restrict__ binBase, int* __restrict__ binCursor,
    int* __restrict__ rowptr, int NB, int E, int N) {
    __shared__ int s[MAXNB];
    int t = threadIdx.x;
    int orig = (t < NB) ? binCount[t] : 0;
    s[t] = orig;
    __syncthreads();
    for (int off = 1; off < MAXNB; off <<= 1) {
        int v = (t >= off) ? s[t - off] : 0;
        __syncthreads();
        s[t] += v;
        __syncthreads();
    }
    int excl = s[t] - orig;
    if (t < NB) { binBase[t] = excl; binCursor[t] = excl; }
    if (t == 0) { binBase[NB] = E; rowptr[N] = E; }
}

// ---------------- scatter edges into dst-buckets: binBuf[pos] = (src,dst) ----------------
// only NB (~391) concurrently-advancing write streams -> L2-resident lines, full fills
__global__ __launch_bounds__(256) void binscatter_kernel(
    const int* __restrict__ eidx, int* __restrict__ binCursor,
    int2* __restrict__ binBuf, int E) {
    int e = blockIdx.x * 256 + threadIdx.x;
    if (e >= E) return;
    int s = eidx[e];
    int d = eidx[E + e];
    int pos = atomicAdd(&binCursor[d >> BSHIFT], 1);
    binBuf[pos] = make_int2(s, d);
}

// ---------------- per-bucket CSR: LDS hist -> LDS scan -> rowptr + col fill ----------------
// all cursor atomics in LDS; col writes land in the bucket's contiguous ~33KB window
__global__ __launch_bounds__(256) void bucket_csr_kernel(
    const int2* __restrict__ binBuf, const int* __restrict__ binBase,
    int* __restrict__ rowptr, int* __restrict__ col, int N) {
    __shared__ int hist[256], lcur[256];
    const int b = blockIdx.x, t = threadIdx.x;
    const int ebeg = binBase[b], eend = binBase[b + 1];
    hist[t] = 0;
    __syncthreads();
    for (int i = ebeg + t; i < eend; i += 256)
        atomicAdd(&hist[binBuf[i].y & 255], 1);
    __syncthreads();
    int orig = hist[t];
    for (int off = 1; off < 256; off <<= 1) {
        int v = (t >= off) ? hist[t - off] : 0;
        __syncthreads();
        hist[t] += v;
        __syncthreads();
    }
    int rp = ebeg + hist[t] - orig;   // exclusive prefix -> global CSR offset
    int node = (b << BSHIFT) + t;
    if (node < N) rowptr[node] = rp;
    lcur[t] = rp;
    __syncthreads();
    for (int i = ebeg + t; i < eend; i += 256) {
        int2 p = binBuf[i];
        int pos = atomicAdd(&lcur[p.y & 255], 1);
        col[pos] = p.x;
    }
}

// ---------------- CSR gather aggregation: agg[i] = sum_{j in N(i)} h[j]  (no atomics) ----------------
__global__ __launch_bounds__(256) void agg_csr_kernel(
    const float* __restrict__ h, const int* __restrict__ rowptr,
    const int* __restrict__ col, float* __restrict__ agg, int N) {
    int node = blockIdx.x * 4 + (threadIdx.x >> 6);
    if (node >= N) return;
    int lane = threadIdx.x & 63;
    int grp = lane >> 4;
    int sub = lane & 15;
    int s = rowptr[node], e = rowptr[node + 1];
    float4 acc = make_float4(0.f, 0.f, 0.f, 0.f);
    int i = s;
    #pragma unroll 2
    for (; i + 4 <= e; i += 4) {
        int c = col[i + grp];
        const float4 v = *(const float4*)&h[(c << 6) + (sub << 2)];
        acc.x += v.x; acc.y += v.y; acc.z += v.z; acc.w += v.w;
    }
    if (i + grp < e) {
        int c = col[i + grp];
        const float4 v = *(const float4*)&h[(c << 6) + (sub << 2)];
        acc.x += v.x; acc.y += v.y; acc.z += v.z; acc.w += v.w;
    }
    acc.x += __shfl_xor(acc.x, 16, 64); acc.y += __shfl_xor(acc.y, 16, 64);
    acc.z += __shfl_xor(acc.z, 16, 64); acc.w += __shfl_xor(acc.w, 16, 64);
    acc.x += __shfl_xor(acc.x, 32, 64); acc.y += __shfl_xor(acc.y, 32, 64);
    acc.z += __shfl_xor(acc.z, 32, 64); acc.w += __shfl_xor(acc.w, 32, 64);
    if (grp == 0) *(float4*)&agg[(node << 6) + (sub << 2)] = acc;
}

// ---------------- fused GIN MLP + pooling contribution ----------------
__global__ __launch_bounds__(256) void mlp_kernel(
    const float* hin, const float* __restrict__ agg,
    const float* __restrict__ x0, const int* __restrict__ batch,
    const float* __restrict__ W1, const float* __restrict__ b1,
    const float* __restrict__ g1, const float* __restrict__ be1,
    const float* __restrict__ W2, const float* __restrict__ b2,
    const float* __restrict__ g2, const float* __restrict__ be2,
    float* hout, float* __restrict__ pooled, int l64, int N) {
    __shared__ __align__(16) float zT[64][68];    // zT[c][r]; later reused row-major as zs[r*68+c]
    __shared__ __align__(16) float Wf[64][64];
    __shared__ float sc[64], bcs[64];
    __shared__ float wsm[ND][64];
    __shared__ int   sgr[64];
    const int t = threadIdx.x;
    const int r0 = blockIdx.x * 64;
    const float inv = rsqrtf(1.0f + 1e-5f);

    if (t < 64) { float s = g1[t] * inv; sc[t] = s; bcs[t] = b1[t] * s + be1[t]; }
    __syncthreads();
    for (int i = t; i < 4096; i += 256) { int c = i & 63; Wf[i >> 6][c] = W1[i] * sc[c]; }
    {
        const int rr = t >> 2;
        const int cq = (t & 3) << 2;
        const int row = r0 + rr;
        #pragma unroll
        for (int j = 0; j < 4; j++) {
            const int c = cq + j * 16;
            float4 v = make_float4(0.f, 0.f, 0.f, 0.f);
            if (row < N) {
                const float4 hv = *(const float4*)&hin[(row << 6) + c];
                const float4 av = *(const float4*)&agg[(row << 6) + c];
                v.x = hv.x + av.x; v.y = hv.y + av.y; v.z = hv.z + av.z; v.w = hv.w + av.w;
            }
            zT[c + 0][rr] = v.x; zT[c + 1][rr] = v.y; zT[c + 2][rr] = v.z; zT[c + 3][rr] = v.w;
        }
    }
    __syncthreads();

    const int ty = t & 15;
    const int tx = t >> 4;

    float acc[4][4];
    #pragma unroll
    for (int i = 0; i < 4; i++)
        #pragma unroll
        for (int j = 0; j < 4; j++) acc[i][j] = bcs[(tx << 2) + j];
    for (int k = 0; k < 64; k++) {
        const float4 zv = *(const float4*)&zT[k][ty << 2];
        const float4 wv = *(const float4*)&Wf[k][tx << 2];
        acc[0][0] = fmaf(zv.x, wv.x, acc[0][0]); acc[0][1] = fmaf(zv.x, wv.y, acc[0][1]);
        acc[0][2] = fmaf(zv.x, wv.z, acc[0][2]); acc[0][3] = fmaf(zv.x, wv.w, acc[0][3]);
        acc[1][0] = fmaf(zv.y, wv.x, acc[1][0]); acc[1][1] = fmaf(zv.y, wv.y, acc[1][1]);
        acc[1][2] = fmaf(zv.y, wv.z, acc[1][2]); acc[1][3] = fmaf(zv.y, wv.w, acc[1][3]);
        acc[2][0] = fmaf(zv.z, wv.x, acc[2][0]); acc[2][1] = fmaf(zv.z, wv.y, acc[2][1]);
        acc[2][2] = fmaf(zv.z, wv.z, acc[2][2]); acc[2][3] = fmaf(zv.z, wv.w, acc[2][3]);
        acc[3][0] = fmaf(zv.w, wv.x, acc[3][0]); acc[3][1] = fmaf(zv.w, wv.y, acc[3][1]);
        acc[3][2] = fmaf(zv.w, wv.z, acc[3][2]); acc[3][3] = fmaf(zv.w, wv.w, acc[3][3]);
    }
    __syncthreads();

    if (t < 64) { float s = g2[t] * inv; sc[t] = s; bcs[t] = b2[t] * s + be2[t]; }
    if (t < 192) {
        int r = t & 63, d = t >> 6;
        int row = r0 + r;
        wsm[d][r] = (row < N) ? x0[(row << 6) + d] : 0.f;
    } else {
        int r = t - 192;
        int row = r0 + r; if (row >= N) row = N - 1;
        sgr[r] = batch[row];
    }
    __syncthreads();
    for (int i = t; i < 4096; i += 256) { int c = i & 63; Wf[i >> 6][c] = W2[i] * sc[c]; }
    #pragma unroll
    for (int j = 0; j < 4; j++) {
        float4 w;
        w.x = fmaxf(acc[0][j], 0.f); w.y = fmaxf(acc[1][j], 0.f);
        w.z = fmaxf(acc[2][j], 0.f); w.w = fmaxf(acc[3][j], 0.f);
        *(float4*)&zT[(tx << 2) + j][ty << 2] = w;
    }
    __syncthreads();

    float acc2[4][4];
    #pragma unroll
    for (int i = 0; i < 4; i++)
        #pragma unroll
        for (int j = 0; j < 4; j++) acc2[i][j] = bcs[(tx << 2) + j];
    for (int k = 0; k < 64; k++) {
        const float4 zv = *(const float4*)&zT[k][ty << 2];
        const float4 wv = *(const float4*)&Wf[k][tx << 2];
        acc2[0][0] = fmaf(zv.x, wv.x, acc2[0][0]); acc2[0][1] = fmaf(zv.x, wv.y, acc2[0][1]);
        acc2[0][2] = fmaf(zv.x, wv.z, acc2[0][2]); acc2[0][3] = fmaf(zv.x, wv.w, acc2[0][3]);
        acc2[1][0] = fmaf(zv.y, wv.x, acc2[1][0]); acc2[1][1] = fmaf(zv.y, wv.y, acc2[1][1]);
        acc2[1][2] = fmaf(zv.y, wv.z, acc2[1][2]); acc2[1][3] = fmaf(zv.y, wv.w, acc2[1][3]);
        acc2[2][0] = fmaf(zv.z, wv.x, acc2[2][0]); acc2[2][1] = fmaf(zv.z, wv.y, acc2[2][1]);
        acc2[2][2] = fmaf(zv.z, wv.z, acc2[2][2]); acc2[2][3] = fmaf(zv.z, wv.w, acc2[2][3]);
        acc2[3][0] = fmaf(zv.w, wv.x, acc2[3][0]); acc2[3][1] = fmaf(zv.w, wv.y, acc2[3][1]);
        acc2[3][2] = fmaf(zv.w, wv.z, acc2[3][2]); acc2[3][3] = fmaf(zv.w, wv.w, acc2[3][3]);
    }
    __syncthreads();

    float* zsf = &zT[0][0];
    #pragma unroll
    for (int i = 0; i < 4; i++) {
        const int r = (ty << 2) + i;
        const int row = r0 + r;
        float4 o;
        o.x = fmaxf(acc2[i][0], 0.f); o.y = fmaxf(acc2[i][1], 0.f);
        o.z = fmaxf(acc2[i][2], 0.f); o.w = fmaxf(acc2[i][3], 0.f);
        if (hout && row < N) *(float4*)&hout[(row << 6) + (tx << 2)] = o;
        *(float4*)&zsf[r * 68 + (tx << 2)] = o;
    }
    __syncthreads();

    {
        const int c = t & 63;
        const int strip = t >> 6;
        float a0 = 0.f, a1 = 0.f, a2 = 0.f;
        int curg = sgr[strip * 16];
        #pragma unroll
        for (int rr = 0; rr < 16; rr++) {
            const int r = strip * 16 + rr;
            const int g = sgr[r];
            if (g != curg) {
                atomicAdd(&pooled[(0 * NG + curg) * 256 + l64 + c], a0);
                atomicAdd(&pooled[(1 * NG + curg) * 256 + l64 + c], a1);
                atomicAdd(&pooled[(2 * NG + curg) * 256 + l64 + c], a2);
                a0 = a1 = a2 = 0.f; curg = g;
            }
            const float v = zsf[r * 68 + c];
            a0 = fmaf(v, wsm[0][r], a0);
            a1 = fmaf(v, wsm[1][r], a1);
            a2 = fmaf(v, wsm[2][r], a2);
        }
        atomicAdd(&pooled[(0 * NG + curg) * 256 + l64 + c], a0);
        atomicAdd(&pooled[(1 * NG + curg) * 256 + l64 + c], a1);
        atomicAdd(&pooled[(2 * NG + curg) * 256 + l64 + c], a2);
    }
}

// ---------------- readout: out = (sum_dim relu(pooled@Wd+bd)) @ Wout + bout ----------------
__global__ __launch_bounds__(64) void readout_kernel(
    const float* __restrict__ pooled, const float* __restrict__ Wd, const float* __restrict__ bd,
    const float* __restrict__ Wout, const float* __restrict__ bout,
    float* __restrict__ out, int C) {
    int g = blockIdx.x, c = threadIdx.x;
    __shared__ float sh[64];
    float v = 0.f;
    for (int dim = 0; dim < ND; dim++) {
        float acc = bd[dim * 64 + c];
        const float* p = pooled + dim * NG * 256 + g * 256;
        const float* wmat = Wd + dim * 256 * 64;
        for (int k = 0; k < 256; k++) acc = fmaf(p[k], wmat[k * 64 + c], acc);
        v += fmaxf(acc, 0.f);
    }
    sh[c] = v;
    __syncthreads();
    if (c < C) {
        float acc = bout[c];
        #pragma unroll
        for (int k = 0; k < 64; k++) acc = fmaf(sh[k], Wout[k * C + c], acc);
        out[g * C + c] = acc;
    }
}

extern "C" void kernel_launch(void* const* d_in, const int* in_sizes, int n_in,
                              void* d_out, int out_size, void* d_ws, size_t ws_size,
                              hipStream_t stream) {
    const float* x     = (const float*)d_in[0];
    const int*   eidx  = (const int*)d_in[1];   // int32 (jax x64 disabled)
    const int*   batch = (const int*)d_in[2];   // int32
    const float* W1  = (const float*)d_in[3];
    const float* b1  = (const float*)d_in[4];
    const float* g1  = (const float*)d_in[5];
    const float* be1 = (const float*)d_in[6];
    const float* W2  = (const float*)d_in[7];
    const float* b2  = (const float*)d_in[8];
    const float* g2  = (const float*)d_in[9];
    const float* be2 = (const float*)d_in[10];
    const float* Wd  = (const float*)d_in[11];
    const float* bd  = (const float*)d_in[12];
    const float* Wo  = (const float*)d_in[13];
    const float* bo  = (const float*)d_in[14];

    const int N = in_sizes[0] / 64;
    const int E = in_sizes[1] / 2;
    const int C = in_sizes[14];
    const int P = ND * NG * 256;
    const int NB = (N + 255) >> BSHIFT;   // buckets of 256 nodes

    // workspace layout (~66 MB); binBuf (8E bytes) overlays agg+hA (dead until layer 0)
    float* ws     = (float*)d_ws;
    float* agg    = ws;                          // N*64 floats
    float* hA     = agg + (size_t)N * 64;        // N*64 floats
    float* pooled = hA + (size_t)N * 64;         // P floats
    int*   ibase  = (int*)(pooled + P);
    int* col       = ibase;                      // E
    int* rowptr    = col + E;                    // N+1
    int* binCount  = rowptr + N + 1;             // NB
    int* binBase   = binCount + NB;              // NB+1
    int* binCursor = binBase + NB + 1;           // NB
    int2* binBuf   = (int2*)ws;                  // E int2 (overlay)

    // guards: ws must hold everything; binBuf must fit in agg+hA overlay; NB <= MAXNB
    size_t need = ((size_t)N * 128 + P) * 4 + ((size_t)E + N + 1 + 3 * (size_t)NB + 2) * 4;
    if (ws_size < need) return;
    if ((size_t)E * 8 > (size_t)N * 128 * 4) return;
    if (NB > MAXNB) return;

    // ---- CSR build: bin -> scan -> scatter -> per-bucket local CSR ----
    {
        int zn = (NB > P ? NB : P);
        zero_kernel<<<(zn + 255) / 256, 256, 0, stream>>>(binCount, pooled, NB, P);
    }
    binhist_kernel<<<(E + 4095) / 4096, 256, 0, stream>>>(eidx, binCount, E, NB);
    binscan_kernel<<<1, MAXNB, 0, stream>>>(binCount, binBase, binCursor, rowptr, NB, E, N);
    binscatter_kernel<<<(E + 255) / 256, 256, 0, stream>>>(eidx, binCursor, binBuf, E);
    bucket_csr_kernel<<<NB, 256, 0, stream>>>(binBuf, binBase, rowptr, col, N);

    // ---- layers: h chain x -> hA -> hA (in-place) -> hA -> (none) ----
    const int mblocks = (N + 63) / 64;
    for (int l = 0; l < NL; l++) {
        const float* hin = (l == 0) ? x : hA;
        float*       hout = (l == NL - 1) ? nullptr : hA;
        agg_csr_kernel<<<(N + 3) / 4, 256, 0, stream>>>(hin, rowptr, col, agg, N);
        mlp_kernel<<<mblocks, 256, 0, stream>>>(
            hin, agg, x, batch,
            W1 + (size_t)l * 4096, b1 + l * 64, g1 + l * 64, be1 + l * 64,
            W2 + (size_t)l * 4096, b2 + l * 64, g2 + l * 64, be2 + l * 64,
            hout, pooled, l * 64, N);
    }

    // ---- readout ----
    readout_kernel<<<NG, 64, 0, stream>>>(pooled, Wd, bd, Wo, bo, (float*)d_out, C);
}

// Round 9
// 1025.880 us; speedup vs baseline: 1.8069x; 1.8069x over previous
//
#include <hip/hip_runtime.h>

#define NG 128     // num graphs
#define NL 4       // layers
#define ND 3       // dims
#define BSHIFT 3   // 8 nodes per bucket
#define BMASK 7

// ---------------- zero binCount + pooled (capture-safe) ----------------
__global__ __launch_bounds__(256) void zero_kernel(
    int* __restrict__ binCount, float* __restrict__ pooled, int NB, int P) {
    int i = blockIdx.x * 256 + threadIdx.x;
    if (i < NB) binCount[i] = 0;
    if (i < P) pooled[i] = 0.f;
}

// ---------------- bucket histogram: 3.2M atomics over 12.5K addresses (~256/chain) ----------------
__global__ __launch_bounds__(256) void binhist_kernel(
    const int* __restrict__ eidx, int* __restrict__ binCount, int E) {
    int e = blockIdx.x * 256 + threadIdx.x;
    if (e >= E) return;
    atomicAdd(&binCount[eidx[E + e] >> BSHIFT], 1);
}

// ---------------- scan pass 1: per-block (1024 elems) sums ----------------
__global__ __launch_bounds__(256) void scan1_kernel(
    const int* __restrict__ cnt, int* __restrict__ partial, int NB) {
    __shared__ int sh[256];
    int t = threadIdx.x;
    int base = blockIdx.x * 1024 + t * 4;
    int ts = 0;
    #pragma unroll
    for (int j = 0; j < 4; j++) { int i = base + j; if (i < NB) ts += cnt[i]; }
    sh[t] = ts;
    __syncthreads();
    for (int off = 128; off > 0; off >>= 1) {
        if (t < off) sh[t] += sh[t + off];
        __syncthreads();
    }
    if (t == 0) partial[blockIdx.x] = sh[0];
}

// ---------------- scan pass 2: serial exclusive scan of partials; set sentinels ----------------
__global__ void scan2_kernel(int* __restrict__ partial, int nb1,
                             int* __restrict__ binBase, int* __restrict__ rowptr,
                             int NB, int E, int N) {
    if (threadIdx.x == 0) {
        int run = 0;
        for (int i = 0; i < nb1; i++) { int v = partial[i]; partial[i] = run; run += v; }
        binBase[NB] = E;
        rowptr[N] = E;
    }
}

// ---------------- scan pass 3: block exclusive scan + offset -> binBase, binCursor ----------------
__global__ __launch_bounds__(256) void scan3_kernel(
    const int* __restrict__ cnt, const int* __restrict__ partial,
    int* __restrict__ binBase, int* __restrict__ binCursor, int NB) {
    __shared__ int sh[256];
    int t = threadIdx.x;
    int base = blockIdx.x * 1024 + t * 4;
    int d[4];
    #pragma unroll
    for (int j = 0; j < 4; j++) { int i = base + j; d[j] = (i < NB) ? cnt[i] : 0; }
    int ts = d[0] + d[1] + d[2] + d[3];
    sh[t] = ts;
    __syncthreads();
    for (int off = 1; off < 256; off <<= 1) {
        int v = (t >= off) ? sh[t - off] : 0;
        __syncthreads();
        sh[t] += v;
        __syncthreads();
    }
    int run = sh[t] - ts + partial[blockIdx.x];
    #pragma unroll
    for (int j = 0; j < 4; j++) {
        int i = base + j;
        if (i < NB) { binBase[i] = run; binCursor[i] = run; }
        run += d[j];
    }
}

// ---------------- scatter edges into dst-buckets (packed: src | dlocal<<24) ----------------
// 12.5K cursor addresses (~256 atomics/chain ~ 35us); 12.5K write streams x 64B = 800KB L2-resident
__global__ __launch_bounds__(256) void binscatter_kernel(
    const int* __restrict__ eidx, int* __restrict__ binCursor,
    int* __restrict__ binBuf, int E) {
    int e = blockIdx.x * 256 + threadIdx.x;
    if (e >= E) return;
    int s = eidx[e];
    int d = eidx[E + e];
    int pos = atomicAdd(&binCursor[d >> BSHIFT], 1);
    binBuf[pos] = s | ((d & BMASK) << 24);
}

// ---------------- per-bucket CSR: LDS hist(8) -> scan -> rowptr + col fill ----------------
__global__ __launch_bounds__(64) void bucket_csr_kernel(
    const int* __restrict__ binBuf, const int* __restrict__ binBase,
    int* __restrict__ rowptr, int* __restrict__ col, int N) {
    __shared__ int hist[8], lcur[8];
    const int b = blockIdx.x, t = threadIdx.x;
    const int ebeg = binBase[b], eend = binBase[b + 1];
    if (t < 8) hist[t] = 0;
    __syncthreads();
    for (int i = ebeg + t; i < eend; i += 64)
        atomicAdd(&hist[(binBuf[i] >> 24) & BMASK], 1);
    __syncthreads();
    if (t < 8) {
        int excl = 0;
        #pragma unroll
        for (int k = 0; k < 8; k++) if (k < t) excl += hist[k];
        int rp = ebeg + excl;
        int node = (b << BSHIFT) + t;
        if (node < N) rowptr[node] = rp;
        lcur[t] = rp;
    }
    __syncthreads();
    for (int i = ebeg + t; i < eend; i += 64) {
        int p = binBuf[i];
        int pos = atomicAdd(&lcur[(p >> 24) & BMASK], 1);
        col[pos] = p & 0x00FFFFFF;
    }
}

// ---------------- CSR gather aggregation: agg[i] = sum_{j in N(i)} h[j]  (no atomics) ----------------
__global__ __launch_bounds__(256) void agg_csr_kernel(
    const float* __restrict__ h, const int* __restrict__ rowptr,
    const int* __restrict__ col, float* __restrict__ agg, int N) {
    int node = blockIdx.x * 4 + (threadIdx.x >> 6);
    if (node >= N) return;
    int lane = threadIdx.x & 63;
    int grp = lane >> 4;
    int sub = lane & 15;
    int s = rowptr[node], e = rowptr[node + 1];
    float4 acc = make_float4(0.f, 0.f, 0.f, 0.f);
    int i = s;
    #pragma unroll 2
    for (; i + 4 <= e; i += 4) {
        int c = col[i + grp];
        const float4 v = *(const float4*)&h[(c << 6) + (sub << 2)];
        acc.x += v.x; acc.y += v.y; acc.z += v.z; acc.w += v.w;
    }
    if (i + grp < e) {
        int c = col[i + grp];
        const float4 v = *(const float4*)&h[(c << 6) + (sub << 2)];
        acc.x += v.x; acc.y += v.y; acc.z += v.z; acc.w += v.w;
    }
    acc.x += __shfl_xor(acc.x, 16, 64); acc.y += __shfl_xor(acc.y, 16, 64);
    acc.z += __shfl_xor(acc.z, 16, 64); acc.w += __shfl_xor(acc.w, 16, 64);
    acc.x += __shfl_xor(acc.x, 32, 64); acc.y += __shfl_xor(acc.y, 32, 64);
    acc.z += __shfl_xor(acc.z, 32, 64); acc.w += __shfl_xor(acc.w, 32, 64);
    if (grp == 0) *(float4*)&agg[(node << 6) + (sub << 2)] = acc;
}

// ---------------- fused GIN MLP + pooling contribution ----------------
__global__ __launch_bounds__(256) void mlp_kernel(
    const float* hin, const float* __restrict__ agg,
    const float* __restrict__ x0, const int* __restrict__ batch,
    const float* __restrict__ W1, const float* __restrict__ b1,
    const float* __restrict__ g1, const float* __restrict__ be1,
    const float* __restrict__ W2, const float* __restrict__ b2,
    const float* __restrict__ g2, const float* __restrict__ be2,
    float* hout, float* __restrict__ pooled, int l64, int N) {
    __shared__ __align__(16) float zT[64][68];    // zT[c][r]; later reused row-major as zs[r*68+c]
    __shared__ __align__(16) float Wf[64][64];
    __shared__ float sc[64], bcs[64];
    __shared__ float wsm[ND][64];
    __shared__ int   sgr[64];
    const int t = threadIdx.x;
    const int r0 = blockIdx.x * 64;
    const float inv = rsqrtf(1.0f + 1e-5f);

    if (t < 64) { float s = g1[t] * inv; sc[t] = s; bcs[t] = b1[t] * s + be1[t]; }
    __syncthreads();
    for (int i = t; i < 4096; i += 256) { int c = i & 63; Wf[i >> 6][c] = W1[i] * sc[c]; }
    {
        const int rr = t >> 2;
        const int cq = (t & 3) << 2;
        const int row = r0 + rr;
        #pragma unroll
        for (int j = 0; j < 4; j++) {
            const int c = cq + j * 16;
            float4 v = make_float4(0.f, 0.f, 0.f, 0.f);
            if (row < N) {
                const float4 hv = *(const float4*)&hin[(row << 6) + c];
                const float4 av = *(const float4*)&agg[(row << 6) + c];
                v.x = hv.x + av.x; v.y = hv.y + av.y; v.z = hv.z + av.z; v.w = hv.w + av.w;
            }
            zT[c + 0][rr] = v.x; zT[c + 1][rr] = v.y; zT[c + 2][rr] = v.z; zT[c + 3][rr] = v.w;
        }
    }
    __syncthreads();

    const int ty = t & 15;
    const int tx = t >> 4;

    float acc[4][4];
    #pragma unroll
    for (int i = 0; i < 4; i++)
        #pragma unroll
        for (int j = 0; j < 4; j++) acc[i][j] = bcs[(tx << 2) + j];
    for (int k = 0; k < 64; k++) {
        const float4 zv = *(const float4*)&zT[k][ty << 2];
        const float4 wv = *(const float4*)&Wf[k][tx << 2];
        acc[0][0] = fmaf(zv.x, wv.x, acc[0][0]); acc[0][1] = fmaf(zv.x, wv.y, acc[0][1]);
        acc[0][2] = fmaf(zv.x, wv.z, acc[0][2]); acc[0][3] = fmaf(zv.x, wv.w, acc[0][3]);
        acc[1][0] = fmaf(zv.y, wv.x, acc[1][0]); acc[1][1] = fmaf(zv.y, wv.y, acc[1][1]);
        acc[1][2] = fmaf(zv.y, wv.z, acc[1][2]); acc[1][3] = fmaf(zv.y, wv.w, acc[1][3]);
        acc[2][0] = fmaf(zv.z, wv.x, acc[2][0]); acc[2][1] = fmaf(zv.z, wv.y, acc[2][1]);
        acc[2][2] = fmaf(zv.z, wv.z, acc[2][2]); acc[2][3] = fmaf(zv.z, wv.w, acc[2][3]);
        acc[3][0] = fmaf(zv.w, wv.x, acc[3][0]); acc[3][1] = fmaf(zv.w, wv.y, acc[3][1]);
        acc[3][2] = fmaf(zv.w, wv.z, acc[3][2]); acc[3][3] = fmaf(zv.w, wv.w, acc[3][3]);
    }
    __syncthreads();

    if (t < 64) { float s = g2[t] * inv; sc[t] = s; bcs[t] = b2[t] * s + be2[t]; }
    if (t < 192) {
        int r = t & 63, d = t >> 6;
        int row = r0 + r;
        wsm[d][r] = (row < N) ? x0[(row << 6) + d] : 0.f;
    } else {
        int r = t - 192;
        int row = r0 + r; if (row >= N) row = N - 1;
        sgr[r] = batch[row];
    }
    __syncthreads();
    for (int i = t; i < 4096; i += 256) { int c = i & 63; Wf[i >> 6][c] = W2[i] * sc[c]; }
    #pragma unroll
    for (int j = 0; j < 4; j++) {
        float4 w;
        w.x = fmaxf(acc[0][j], 0.f); w.y = fmaxf(acc[1][j], 0.f);
        w.z = fmaxf(acc[2][j], 0.f); w.w = fmaxf(acc[3][j], 0.f);
        *(float4*)&zT[(tx << 2) + j][ty << 2] = w;
    }
    __syncthreads();

    float acc2[4][4];
    #pragma unroll
    for (int i = 0; i < 4; i++)
        #pragma unroll
        for (int j = 0; j < 4; j++) acc2[i][j] = bcs[(tx << 2) + j];
    for (int k = 0; k < 64; k++) {
        const float4 zv = *(const float4*)&zT[k][ty << 2];
        const float4 wv = *(const float4*)&Wf[k][tx << 2];
        acc2[0][0] = fmaf(zv.x, wv.x, acc2[0][0]); acc2[0][1] = fmaf(zv.x, wv.y, acc2[0][1]);
        acc2[0][2] = fmaf(zv.x, wv.z, acc2[0][2]); acc2[0][3] = fmaf(zv.x, wv.w, acc2[0][3]);
        acc2[1][0] = fmaf(zv.y, wv.x, acc2[1][0]); acc2[1][1] = fmaf(zv.y, wv.y, acc2[1][1]);
        acc2[1][2] = fmaf(zv.y, wv.z, acc2[1][2]); acc2[1][3] = fmaf(zv.y, wv.w, acc2[1][3]);
        acc2[2][0] = fmaf(zv.z, wv.x, acc2[2][0]); acc2[2][1] = fmaf(zv.z, wv.y, acc2[2][1]);
        acc2[2][2] = fmaf(zv.z, wv.z, acc2[2][2]); acc2[2][3] = fmaf(zv.z, wv.w, acc2[2][3]);
        acc2[3][0] = fmaf(zv.w, wv.x, acc2[3][0]); acc2[3][1] = fmaf(zv.w, wv.y, acc2[3][1]);
        acc2[3][2] = fmaf(zv.w, wv.z, acc2[3][2]); acc2[3][3] = fmaf(zv.w, wv.w, acc2[3][3]);
    }
    __syncthreads();

    float* zsf = &zT[0][0];
    #pragma unroll
    for (int i = 0; i < 4; i++) {
        const int r = (ty << 2) + i;
        const int row = r0 + r;
        float4 o;
        o.x = fmaxf(acc2[i][0], 0.f); o.y = fmaxf(acc2[i][1], 0.f);
        o.z = fmaxf(acc2[i][2], 0.f); o.w = fmaxf(acc2[i][3], 0.f);
        if (hout && row < N) *(float4*)&hout[(row << 6) + (tx << 2)] = o;
        *(float4*)&zsf[r * 68 + (tx << 2)] = o;
    }
    __syncthreads();

    {
        const int c = t & 63;
        const int strip = t >> 6;
        float a0 = 0.f, a1 = 0.f, a2 = 0.f;
        int curg = sgr[strip * 16];
        #pragma unroll
        for (int rr = 0; rr < 16; rr++) {
            const int r = strip * 16 + rr;
            const int g = sgr[r];
            if (g != curg) {
                atomicAdd(&pooled[(0 * NG + curg) * 256 + l64 + c], a0);
                atomicAdd(&pooled[(1 * NG + curg) * 256 + l64 + c], a1);
                atomicAdd(&pooled[(2 * NG + curg) * 256 + l64 + c], a2);
                a0 = a1 = a2 = 0.f; curg = g;
            }
            const float v = zsf[r * 68 + c];
            a0 = fmaf(v, wsm[0][r], a0);
            a1 = fmaf(v, wsm[1][r], a1);
            a2 = fmaf(v, wsm[2][r], a2);
        }
        atomicAdd(&pooled[(0 * NG + curg) * 256 + l64 + c], a0);
        atomicAdd(&pooled[(1 * NG + curg) * 256 + l64 + c], a1);
        atomicAdd(&pooled[(2 * NG + curg) * 256 + l64 + c], a2);
    }
}

// ---------------- readout: out = (sum_dim relu(pooled@Wd+bd)) @ Wout + bout ----------------
__global__ __launch_bounds__(64) void readout_kernel(
    const float* __restrict__ pooled, const float* __restrict__ Wd, const float* __restrict__ bd,
    const float* __restrict__ Wout, const float* __restrict__ bout,
    float* __restrict__ out, int C) {
    int g = blockIdx.x, c = threadIdx.x;
    __shared__ float sh[64];
    float v = 0.f;
    for (int dim = 0; dim < ND; dim++) {
        float acc = bd[dim * 64 + c];
        const float* p = pooled + dim * NG * 256 + g * 256;
        const float* wmat = Wd + dim * 256 * 64;
        for (int k = 0; k < 256; k++) acc = fmaf(p[k], wmat[k * 64 + c], acc);
        v += fmaxf(acc, 0.f);
    }
    sh[c] = v;
    __syncthreads();
    if (c < C) {
        float acc = bout[c];
        #pragma unroll
        for (int k = 0; k < 64; k++) acc = fmaf(sh[k], Wout[k * C + c], acc);
        out[g * C + c] = acc;
    }
}

extern "C" void kernel_launch(void* const* d_in, const int* in_sizes, int n_in,
                              void* d_out, int out_size, void* d_ws, size_t ws_size,
                              hipStream_t stream) {
    const float* x     = (const float*)d_in[0];
    const int*   eidx  = (const int*)d_in[1];   // int32 (jax x64 disabled)
    const int*   batch = (const int*)d_in[2];   // int32
    const float* W1  = (const float*)d_in[3];
    const float* b1  = (const float*)d_in[4];
    const float* g1  = (const float*)d_in[5];
    const float* be1 = (const float*)d_in[6];
    const float* W2  = (const float*)d_in[7];
    const float* b2  = (const float*)d_in[8];
    const float* g2  = (const float*)d_in[9];
    const float* be2 = (const float*)d_in[10];
    const float* Wd  = (const float*)d_in[11];
    const float* bd  = (const float*)d_in[12];
    const float* Wo  = (const float*)d_in[13];
    const float* bo  = (const float*)d_in[14];

    const int N = in_sizes[0] / 64;
    const int E = in_sizes[1] / 2;
    const int C = in_sizes[14];
    const int P = ND * NG * 256;
    const int NB = (N + BMASK) >> BSHIFT;   // 8-node buckets

    // persistent layout (~64.8 MB): agg | hA | pooled | col | rowptr
    float* ws     = (float*)d_ws;
    float* agg    = ws;                          // N*64 floats   (region A start)
    float* hA     = agg + (size_t)N * 64;        // N*64 floats
    float* pooled = hA + (size_t)N * 64;         // P floats
    int*   col    = (int*)(pooled + P);          // E ints
    int*   rowptr = col + E;                     // N+1 ints
    // CSR-build temporaries overlay region A (agg+hA, dead until layers start)
    int* binBuf    = (int*)ws;                   // E ints (packed src | dlocal<<24)
    int* binCount  = binBuf + E;                 // NB
    int* binBase   = binCount + NB;              // NB+1
    int* binCursor = binBase + NB + 1;           // NB
    int* partial   = binCursor + NB;             // <=64

    const int nb1 = (NB + 1023) / 1024;          // scan blocks over buckets

    // guards (deterministic, capture-safe)
    size_t need = ((size_t)N * 128 + P) * 4 + ((size_t)E + N + 1) * 4;
    size_t ovl  = ((size_t)E + 3 * (size_t)NB + 66) * 4;
    if (ws_size < need) return;
    if (ovl > (size_t)N * 128 * 4) return;
    if (N >= (1 << 24) || nb1 > 64) return;

    // ---- CSR build: hist -> scan -> scatter(packed) -> per-bucket CSR ----
    {
        int zn = (NB > P ? NB : P);
        zero_kernel<<<(zn + 255) / 256, 256, 0, stream>>>(binCount, pooled, NB, P);
    }
    binhist_kernel<<<(E + 255) / 256, 256, 0, stream>>>(eidx, binCount, E);
    scan1_kernel<<<nb1, 256, 0, stream>>>(binCount, partial, NB);
    scan2_kernel<<<1, 64, 0, stream>>>(partial, nb1, binBase, rowptr, NB, E, N);
    scan3_kernel<<<nb1, 256, 0, stream>>>(binCount, partial, binBase, binCursor, NB);
    binscatter_kernel<<<(E + 255) / 256, 256, 0, stream>>>(eidx, binCursor, binBuf, E);
    bucket_csr_kernel<<<NB, 64, 0, stream>>>(binBuf, binBase, rowptr, col, N);

    // ---- layers: h chain x -> hA -> hA (in-place) -> hA -> (none) ----
    const int mblocks = (N + 63) / 64;
    for (int l = 0; l < NL; l++) {
        const float* hin = (l == 0) ? x : hA;
        float*       hout = (l == NL - 1) ? nullptr : hA;
        agg_csr_kernel<<<(N + 3) / 4, 256, 0, stream>>>(hin, rowptr, col, agg, N);
        mlp_kernel<<<mblocks, 256, 0, stream>>>(
            hin, agg, x, batch,
            W1 + (size_t)l * 4096, b1 + l * 64, g1 + l * 64, be1 + l * 64,
            W2 + (size_t)l * 4096, b2 + l * 64, g2 + l * 64, be2 + l * 64,
            hout, pooled, l * 64, N);
    }

    // ---- readout ----
    readout_kernel<<<NG, 64, 0, stream>>>(pooled, Wd, bd, Wo, bo, (float*)d_out, C);
}

// Round 14
// 765.690 us; speedup vs baseline: 2.4209x; 1.3398x over previous
//
#include <hip/hip_runtime.h>

#define NG 128      // num graphs
#define NL 4        // layers
#define ND 3        // dims
#define BSHIFT 8    // 256 nodes per bucket
#define BMASK 255
#define NBMAX 512   // max buckets (N <= 131072)
#define TILE_E 8192 // edges per multisplit tile

// ---------------- zero pooled (capture-safe) ----------------
__global__ __launch_bounds__(256) void zero_kernel(float* __restrict__ pooled, int P) {
    int i = blockIdx.x * 256 + threadIdx.x;
    if (i < P) pooled[i] = 0.f;
}

// ---------------- multisplit pass 1: per-tile LDS histogram over buckets ----------------
__global__ __launch_bounds__(256) void histA_kernel(
    const int* __restrict__ eidx, int* __restrict__ counts, int E, int nWG, int NB) {
    __shared__ int cnt[NBMAX];
    const int t = threadIdx.x, tile = blockIdx.x;
    for (int i = t; i < NB; i += 256) cnt[i] = 0;
    __syncthreads();
    int base = tile * TILE_E;
    int end = base + TILE_E; if (end > E) end = E;
    for (int i = base + t; i < end; i += 256)
        atomicAdd(&cnt[eidx[E + i] >> BSHIFT], 1);   // LDS atomic
    __syncthreads();
    for (int b = t; b < NB; b += 256)
        counts[(size_t)b * nWG + tile] = cnt[b];     // bucket-major
}

// ---------------- scan pass 1: per-block (1024 elems) sums ----------------
__global__ __launch_bounds__(256) void scan1_kernel(
    const int* __restrict__ cnt, int* __restrict__ partial, int M) {
    __shared__ int sh[256];
    int t = threadIdx.x;
    int base = blockIdx.x * 1024 + t * 4;
    int ts = 0;
    #pragma unroll
    for (int j = 0; j < 4; j++) { int i = base + j; if (i < M) ts += cnt[i]; }
    sh[t] = ts;
    __syncthreads();
    for (int off = 128; off > 0; off >>= 1) {
        if (t < off) sh[t] += sh[t + off];
        __syncthreads();
    }
    if (t == 0) partial[blockIdx.x] = sh[0];
}

// ---------------- scan pass 2: serial exclusive scan of partials; sentinels ----------------
__global__ void scan2_kernel(int* __restrict__ partial, int nb1,
                             int* __restrict__ binBase, int* __restrict__ rowptr,
                             int NB, int E, int N) {
    if (threadIdx.x == 0) {
        int run = 0;
        for (int i = 0; i < nb1; i++) { int v = partial[i]; partial[i] = run; run += v; }
        binBase[NB] = E;
        rowptr[N] = E;
    }
}

// ---------------- scan pass 3: block exclusive scan (in-place) + binBase extraction ----------------
__global__ __launch_bounds__(256) void scan3_kernel(
    int* __restrict__ counts, const int* __restrict__ partial,
    int* __restrict__ binBase, int M, int nWG) {
    __shared__ int sh[256];
    int t = threadIdx.x;
    int base = blockIdx.x * 1024 + t * 4;
    int d[4];
    #pragma unroll
    for (int j = 0; j < 4; j++) { int i = base + j; d[j] = (i < M) ? counts[i] : 0; }
    int ts = d[0] + d[1] + d[2] + d[3];
    sh[t] = ts;
    __syncthreads();
    for (int off = 1; off < 256; off <<= 1) {
        int v = (t >= off) ? sh[t - off] : 0;
        __syncthreads();
        sh[t] += v;
        __syncthreads();
    }
    int run = sh[t] - ts + partial[blockIdx.x];
    #pragma unroll
    for (int j = 0; j < 4; j++) {
        int i = base + j;
        if (i < M) {
            counts[i] = run;
            if (i % nWG == 0) binBase[i / nWG] = run;   // window start of bucket
        }
        run += d[j];
    }
}

// ---------------- multisplit pass 2: scatter via private windows (LDS cursors, NO global atomics) ----------------
__global__ __launch_bounds__(256) void scatA_kernel(
    const int* __restrict__ eidx, const int* __restrict__ counts,
    int* __restrict__ binBuf, int E, int nWG, int NB) {
    __shared__ int cur[NBMAX];
    const int t = threadIdx.x, tile = blockIdx.x;
    for (int b = t; b < NB; b += 256) cur[b] = counts[(size_t)b * nWG + tile];
    __syncthreads();
    int base = tile * TILE_E;
    int end = base + TILE_E; if (end > E) end = E;
    for (int i = base + t; i < end; i += 256) {
        int s = eidx[i];
        int d = eidx[E + i];
        int pos = atomicAdd(&cur[d >> BSHIFT], 1);   // LDS atomic
        binBuf[pos] = s | ((d & BMASK) << 24);
    }
}

// ---------------- per-bucket CSR: LDS hist -> scan -> rowptr + col fill ----------------
__global__ __launch_bounds__(256) void bucket_csr_kernel(
    const int* __restrict__ binBuf, const int* __restrict__ binBase,
    int* __restrict__ rowptr, int* __restrict__ col, int N) {
    __shared__ int hist[256], lcur[256];
    const int b = blockIdx.x, t = threadIdx.x;
    const int ebeg = binBase[b], eend = binBase[b + 1];
    hist[t] = 0;
    __syncthreads();
    for (int i = ebeg + t; i < eend; i += 256)
        atomicAdd(&hist[(binBuf[i] >> 24) & BMASK], 1);
    __syncthreads();
    int orig = hist[t];
    for (int off = 1; off < 256; off <<= 1) {
        int v = (t >= off) ? hist[t - off] : 0;
        __syncthreads();
        hist[t] += v;
        __syncthreads();
    }
    int rp = ebeg + hist[t] - orig;
    int node = (b << BSHIFT) + t;
    if (node < N) rowptr[node] = rp;
    lcur[t] = rp;
    __syncthreads();
    for (int i = ebeg + t; i < eend; i += 256) {
        int p = binBuf[i];
        int pos = atomicAdd(&lcur[(p >> 24) & BMASK], 1);
        col[pos] = p & 0x00FFFFFF;
    }
}

// ---------------- CSR gather aggregation: agg[i] = sum_{j in N(i)} h[j]  (no atomics) ----------------
__global__ __launch_bounds__(256) void agg_csr_kernel(
    const float* __restrict__ h, const int* __restrict__ rowptr,
    const int* __restrict__ col, float* __restrict__ agg, int N) {
    int node = blockIdx.x * 4 + (threadIdx.x >> 6);
    if (node >= N) return;
    int lane = threadIdx.x & 63;
    int grp = lane >> 4;
    int sub = lane & 15;
    int s = rowptr[node], e = rowptr[node + 1];
    float4 acc = make_float4(0.f, 0.f, 0.f, 0.f);
    int i = s;
    #pragma unroll 2
    for (; i + 4 <= e; i += 4) {
        int c = col[i + grp];
        const float4 v = *(const float4*)&h[(c << 6) + (sub << 2)];
        acc.x += v.x; acc.y += v.y; acc.z += v.z; acc.w += v.w;
    }
    if (i + grp < e) {
        int c = col[i + grp];
        const float4 v = *(const float4*)&h[(c << 6) + (sub << 2)];
        acc.x += v.x; acc.y += v.y; acc.z += v.z; acc.w += v.w;
    }
    acc.x += __shfl_xor(acc.x, 16, 64); acc.y += __shfl_xor(acc.y, 16, 64);
    acc.z += __shfl_xor(acc.z, 16, 64); acc.w += __shfl_xor(acc.w, 16, 64);
    acc.x += __shfl_xor(acc.x, 32, 64); acc.y += __shfl_xor(acc.y, 32, 64);
    acc.z += __shfl_xor(acc.z, 32, 64); acc.w += __shfl_xor(acc.w, 32, 64);
    if (grp == 0) *(float4*)&agg[(node << 6) + (sub << 2)] = acc;
}

// ---------------- fused GIN MLP + pooling contribution ----------------
__global__ __launch_bounds__(256) void mlp_kernel(
    const float* hin, const float* __restrict__ agg,
    const float* __restrict__ x0, const int* __restrict__ batch,
    const float* __restrict__ W1, const float* __restrict__ b1,
    const float* __restrict__ g1, const float* __restrict__ be1,
    const float* __restrict__ W2, const float* __restrict__ b2,
    const float* __restrict__ g2, const float* __restrict__ be2,
    float* hout, float* __restrict__ pooled, int l64, int N) {
    __shared__ __align__(16) float zT[64][68];    // zT[c][r]; later reused row-major as zs[r*68+c]
    __shared__ __align__(16) float Wf[64][64];
    __shared__ float sc[64], bcs[64];
    __shared__ float wsm[ND][64];
    __shared__ int   sgr[64];
    const int t = threadIdx.x;
    const int r0 = blockIdx.x * 64;
    const float inv = rsqrtf(1.0f + 1e-5f);

    if (t < 64) { float s = g1[t] * inv; sc[t] = s; bcs[t] = b1[t] * s + be1[t]; }
    __syncthreads();
    for (int i = t; i < 4096; i += 256) { int c = i & 63; Wf[i >> 6][c] = W1[i] * sc[c]; }
    {
        const int rr = t >> 2;
        const int cq = (t & 3) << 2;
        const int row = r0 + rr;
        #pragma unroll
        for (int j = 0; j < 4; j++) {
            const int c = cq + j * 16;
            float4 v = make_float4(0.f, 0.f, 0.f, 0.f);
            if (row < N) {
                const float4 hv = *(const float4*)&hin[(row << 6) + c];
                const float4 av = *(const float4*)&agg[(row << 6) + c];
                v.x = hv.x + av.x; v.y = hv.y + av.y; v.z = hv.z + av.z; v.w = hv.w + av.w;
            }
            zT[c + 0][rr] = v.x; zT[c + 1][rr] = v.y; zT[c + 2][rr] = v.z; zT[c + 3][rr] = v.w;
        }
    }
    __syncthreads();

    const int ty = t & 15;
    const int tx = t >> 4;

    float acc[4][4];
    #pragma unroll
    for (int i = 0; i < 4; i++)
        #pragma unroll
        for (int j = 0; j < 4; j++) acc[i][j] = bcs[(tx << 2) + j];
    for (int k = 0; k < 64; k++) {
        const float4 zv = *(const float4*)&zT[k][ty << 2];
        const float4 wv = *(const float4*)&Wf[k][tx << 2];
        acc[0][0] = fmaf(zv.x, wv.x, acc[0][0]); acc[0][1] = fmaf(zv.x, wv.y, acc[0][1]);
        acc[0][2] = fmaf(zv.x, wv.z, acc[0][2]); acc[0][3] = fmaf(zv.x, wv.w, acc[0][3]);
        acc[1][0] = fmaf(zv.y, wv.x, acc[1][0]); acc[1][1] = fmaf(zv.y, wv.y, acc[1][1]);
        acc[1][2] = fmaf(zv.y, wv.z, acc[1][2]); acc[1][3] = fmaf(zv.y, wv.w, acc[1][3]);
        acc[2][0] = fmaf(zv.z, wv.x, acc[2][0]); acc[2][1] = fmaf(zv.z, wv.y, acc[2][1]);
        acc[2][2] = fmaf(zv.z, wv.z, acc[2][2]); acc[2][3] = fmaf(zv.z, wv.w, acc[2][3]);
        acc[3][0] = fmaf(zv.w, wv.x, acc[3][0]); acc[3][1] = fmaf(zv.w, wv.y, acc[3][1]);
        acc[3][2] = fmaf(zv.w, wv.z, acc[3][2]); acc[3][3] = fmaf(zv.w, wv.w, acc[3][3]);
    }
    __syncthreads();

    if (t < 64) { float s = g2[t] * inv; sc[t] = s; bcs[t] = b2[t] * s + be2[t]; }
    if (t < 192) {
        int r = t & 63, d = t >> 6;
        int row = r0 + r;
        wsm[d][r] = (row < N) ? x0[(row << 6) + d] : 0.f;
    } else {
        int r = t - 192;
        int row = r0 + r; if (row >= N) row = N - 1;
        sgr[r] = batch[row];
    }
    __syncthreads();
    for (int i = t; i < 4096; i += 256) { int c = i & 63; Wf[i >> 6][c] = W2[i] * sc[c]; }
    #pragma unroll
    for (int j = 0; j < 4; j++) {
        float4 w;
        w.x = fmaxf(acc[0][j], 0.f); w.y = fmaxf(acc[1][j], 0.f);
        w.z = fmaxf(acc[2][j], 0.f); w.w = fmaxf(acc[3][j], 0.f);
        *(float4*)&zT[(tx << 2) + j][ty << 2] = w;
    }
    __syncthreads();

    float acc2[4][4];
    #pragma unroll
    for (int i = 0; i < 4; i++)
        #pragma unroll
        for (int j = 0; j < 4; j++) acc2[i][j] = bcs[(tx << 2) + j];
    for (int k = 0; k < 64; k++) {
        const float4 zv = *(const float4*)&zT[k][ty << 2];
        const float4 wv = *(const float4*)&Wf[k][tx << 2];
        acc2[0][0] = fmaf(zv.x, wv.x, acc2[0][0]); acc2[0][1] = fmaf(zv.x, wv.y, acc2[0][1]);
        acc2[0][2] = fmaf(zv.x, wv.z, acc2[0][2]); acc2[0][3] = fmaf(zv.x, wv.w, acc2[0][3]);
        acc2[1][0] = fmaf(zv.y, wv.x, acc2[1][0]); acc2[1][1] = fmaf(zv.y, wv.y, acc2[1][1]);
        acc2[1][2] = fmaf(zv.y, wv.z, acc2[1][2]); acc2[1][3] = fmaf(zv.y, wv.w, acc2[1][3]);
        acc2[2][0] = fmaf(zv.z, wv.x, acc2[2][0]); acc2[2][1] = fmaf(zv.z, wv.y, acc2[2][1]);
        acc2[2][2] = fmaf(zv.z, wv.z, acc2[2][2]); acc2[2][3] = fmaf(zv.z, wv.w, acc2[2][3]);
        acc2[3][0] = fmaf(zv.w, wv.x, acc2[3][0]); acc2[3][1] = fmaf(zv.w, wv.y, acc2[3][1]);
        acc2[3][2] = fmaf(zv.w, wv.z, acc2[3][2]); acc2[3][3] = fmaf(zv.w, wv.w, acc2[3][3]);
    }
    __syncthreads();

    float* zsf = &zT[0][0];
    #pragma unroll
    for (int i = 0; i < 4; i++) {
        const int r = (ty << 2) + i;
        const int row = r0 + r;
        float4 o;
        o.x = fmaxf(acc2[i][0], 0.f); o.y = fmaxf(acc2[i][1], 0.f);
        o.z = fmaxf(acc2[i][2], 0.f); o.w = fmaxf(acc2[i][3], 0.f);
        if (hout && row < N) *(float4*)&hout[(row << 6) + (tx << 2)] = o;
        *(float4*)&zsf[r * 68 + (tx << 2)] = o;
    }
    __syncthreads();

    {
        const int c = t & 63;
        const int strip = t >> 6;
        float a0 = 0.f, a1 = 0.f, a2 = 0.f;
        int curg = sgr[strip * 16];
        #pragma unroll
        for (int rr = 0; rr < 16; rr++) {
            const int r = strip * 16 + rr;
            const int g = sgr[r];
            if (g != curg) {
                atomicAdd(&pooled[(0 * NG + curg) * 256 + l64 + c], a0);
                atomicAdd(&pooled[(1 * NG + curg) * 256 + l64 + c], a1);
                atomicAdd(&pooled[(2 * NG + curg) * 256 + l64 + c], a2);
                a0 = a1 = a2 = 0.f; curg = g;
            }
            const float v = zsf[r * 68 + c];
            a0 = fmaf(v, wsm[0][r], a0);
            a1 = fmaf(v, wsm[1][r], a1);
            a2 = fmaf(v, wsm[2][r], a2);
        }
        atomicAdd(&pooled[(0 * NG + curg) * 256 + l64 + c], a0);
        atomicAdd(&pooled[(1 * NG + curg) * 256 + l64 + c], a1);
        atomicAdd(&pooled[(2 * NG + curg) * 256 + l64 + c], a2);
    }
}

// ---------------- readout: out = (sum_dim relu(pooled@Wd+bd)) @ Wout + bout ----------------
__global__ __launch_bounds__(64) void readout_kernel(
    const float* __restrict__ pooled, const float* __restrict__ Wd, const float* __restrict__ bd,
    const float* __restrict__ Wout, const float* __restrict__ bout,
    float* __restrict__ out, int C) {
    int g = blockIdx.x, c = threadIdx.x;
    __shared__ float sh[64];
    float v = 0.f;
    for (int dim = 0; dim < ND; dim++) {
        float acc = bd[dim * 64 + c];
        const float* p = pooled + dim * NG * 256 + g * 256;
        const float* wmat = Wd + dim * 256 * 64;
        for (int k = 0; k < 256; k++) acc = fmaf(p[k], wmat[k * 64 + c], acc);
        v += fmaxf(acc, 0.f);
    }
    sh[c] = v;
    __syncthreads();
    if (c < C) {
        float acc = bout[c];
        #pragma unroll
        for (int k = 0; k < 64; k++) acc = fmaf(sh[k], Wout[k * C + c], acc);
        out[g * C + c] = acc;
    }
}

extern "C" void kernel_launch(void* const* d_in, const int* in_sizes, int n_in,
                              void* d_out, int out_size, void* d_ws, size_t ws_size,
                              hipStream_t stream) {
    const float* x     = (const float*)d_in[0];
    const int*   eidx  = (const int*)d_in[1];   // int32 (jax x64 disabled)
    const int*   batch = (const int*)d_in[2];   // int32
    const float* W1  = (const float*)d_in[3];
    const float* b1  = (const float*)d_in[4];
    const float* g1  = (const float*)d_in[5];
    const float* be1 = (const float*)d_in[6];
    const float* W2  = (const float*)d_in[7];
    const float* b2  = (const float*)d_in[8];
    const float* g2  = (const float*)d_in[9];
    const float* be2 = (const float*)d_in[10];
    const float* Wd  = (const float*)d_in[11];
    const float* bd  = (const float*)d_in[12];
    const float* Wo  = (const float*)d_in[13];
    const float* bo  = (const float*)d_in[14];

    const int N = in_sizes[0] / 64;
    const int E = in_sizes[1] / 2;
    const int C = in_sizes[14];
    const int P = ND * NG * 256;
    const int NB  = (N + BMASK) >> BSHIFT;       // 256-node buckets
    const int nWG = (E + TILE_E - 1) / TILE_E;   // multisplit tiles
    const size_t M = (size_t)NB * nWG;           // counts elements

    // persistent layout (~64.8 MB): agg | hA | pooled | col | rowptr
    float* ws     = (float*)d_ws;
    float* agg    = ws;                          // N*64 floats   (region A)
    float* hA     = agg + (size_t)N * 64;        // N*64 floats
    float* pooled = hA + (size_t)N * 64;         // P floats
    int*   col    = (int*)(pooled + P);          // E ints
    int*   rowptr = col + E;                     // N+1 ints
    // CSR-build temporaries overlay region A (agg+hA dead until layers start)
    int* binBuf  = (int*)ws;                     // E ints (packed src | dlocal<<24)
    int* counts  = binBuf + E;                   // M ints
    int* binBase = counts + M;                   // NB+1
    int* partial = binBase + NB + 1;             // <=256

    const int nb1 = (int)((M + 1023) / 1024);    // scan blocks over counts

    // guards (deterministic, capture-safe)
    size_t need = ((size_t)N * 128 + P) * 4 + ((size_t)E + N + 1) * 4;
    size_t ovl  = ((size_t)E + M + NB + 1 + 256) * 4;
    if (ws_size < need) return;
    if (ovl > (size_t)N * 128 * 4) return;
    if (N >= (1 << 24) || NB > NBMAX || nb1 > 256) return;

    // ---- CSR build: multisplit (hist -> scan -> windowed scatter) -> per-bucket CSR ----
    zero_kernel<<<(P + 255) / 256, 256, 0, stream>>>(pooled, P);
    histA_kernel<<<nWG, 256, 0, stream>>>(eidx, counts, E, nWG, NB);
    scan1_kernel<<<nb1, 256, 0, stream>>>(counts, partial, (int)M);
    scan2_kernel<<<1, 64, 0, stream>>>(partial, nb1, binBase, rowptr, NB, E, N);
    scan3_kernel<<<nb1, 256, 0, stream>>>(counts, partial, binBase, (int)M, nWG);
    scatA_kernel<<<nWG, 256, 0, stream>>>(eidx, counts, binBuf, E, nWG, NB);
    bucket_csr_kernel<<<NB, 256, 0, stream>>>(binBuf, binBase, rowptr, col, N);

    // ---- layers: h chain x -> hA -> hA (in-place) -> hA -> (none) ----
    const int mblocks = (N + 63) / 64;
    for (int l = 0; l < NL; l++) {
        const float* hin = (l == 0) ? x : hA;
        float*       hout = (l == NL - 1) ? nullptr : hA;
        agg_csr_kernel<<<(N + 3) / 4, 256, 0, stream>>>(hin, rowptr, col, agg, N);
        mlp_kernel<<<mblocks, 256, 0, stream>>>(
            hin, agg, x, batch,
            W1 + (size_t)l * 4096, b1 + l * 64, g1 + l * 64, be1 + l * 64,
            W2 + (size_t)l * 4096, b2 + l * 64, g2 + l * 64, be2 + l * 64,
            hout, pooled, l * 64, N);
    }

    // ---- readout ----
    readout_kernel<<<NG, 64, 0, stream>>>(pooled, Wd, bd, Wo, bo, (float*)d_out, C);
}